// Round 3
// baseline (1684.779 us; speedup 1.0000x reference)
//
#include <hip/hip_runtime.h>
#include <hip/hip_bf16.h>
#include <cstdint>

#define NPTS (1u << 20)
#define CDIM 128
#define NSEG 4096

typedef __attribute__((ext_vector_type(8))) short short8;
typedef __attribute__((ext_vector_type(4))) float f32x4;

__device__ __forceinline__ uint32_t bf16rne(float f) {
    uint32_t u = __float_as_uint(f);
    return (u + 0x7fffu + ((u >> 16) & 1u)) >> 16;
}
__device__ __forceinline__ uint32_t pack2(float a, float b) {
    union { __hip_bfloat162 h; uint32_t u; } cv;
    cv.h = __float22bfloat162_rn(make_float2(a, b));  // v_cvt_pk_bf16_f32, RNE
    return cv.u;
}
// mish(x) = x*tanh(softplus(x)) = x*(t^2+2t)/(t^2+2t+2), t=e^x (exact identity)
__device__ __forceinline__ float mish_f(float x) {
    float t = __expf(x);
    float u = t * (t + 2.0f);
    float m = x * u * __builtin_amdgcn_rcpf(u + 2.0f);
    return (x > 15.0f) ? x : m;
}

// block-wide per-channel reduce; thread t owns channels (t&15)*8+e.
// Returns (for tid<128) the block sum for channel tid. red needs 2048 floats.
template <int OP>  // 0=sum 1=max 2=min
__device__ __forceinline__ float block_reduce_128(float (&vals)[8], float* red) {
    int tid = threadIdx.x;
#pragma unroll
    for (int e = 0; e < 8; e++) red[tid * 8 + e] = vals[e];
    __syncthreads();
    float a = (OP == 0) ? 0.f : (OP == 1 ? -3.4e38f : 3.4e38f);
    if (tid < 128) {
        int cg = tid >> 3, e = tid & 7;
#pragma unroll
        for (int r = 0; r < 16; r++) {
            float x = red[(cg + (r << 4)) * 8 + e];
            if (OP == 0) a += x;
            else if (OP == 1) a = fmaxf(a, x);
            else a = fminf(a, x);
        }
    }
    __syncthreads();
    return a;
}

// ---------------- k0: h0 = mish(points @ w_first + b_first) (bf16) + partial stats
__global__ __launch_bounds__(256) void k_first(const float2* __restrict__ pts,
                                               const float* __restrict__ wf,
                                               const float* __restrict__ bf,
                                               uint16_t* __restrict__ hout,
                                               float* __restrict__ partials) {
    int tid = threadIdx.x;
    int colg = tid & 15;
    int rowt = tid >> 4;
    float w0[8], w1[8], bb[8];
#pragma unroll
    for (int e = 0; e < 8; e++) {
        w0[e] = wf[colg * 8 + e];
        w1[e] = wf[128 + colg * 8 + e];
        bb[e] = bf[colg * 8 + e];
    }
    float ssum[8], ssq[8];
#pragma unroll
    for (int e = 0; e < 8; e++) { ssum[e] = 0.f; ssq[e] = 0.f; }

    int base = blockIdx.x * 256;
    for (int p = 0; p < 16; p++) {
        int pi = base + p * 16 + rowt;
        float2 pt = pts[pi];
        float v[8];
#pragma unroll
        for (int e = 0; e < 8; e++) {
            float x = fmaf(pt.x, w0[e], fmaf(pt.y, w1[e], bb[e]));
            v[e] = mish_f(x);
            ssum[e] += v[e];
            ssq[e] += v[e] * v[e];
        }
        uint4 o;
        o.x = pack2(v[0], v[1]); o.y = pack2(v[2], v[3]);
        o.z = pack2(v[4], v[5]); o.w = pack2(v[6], v[7]);
        *(uint4*)(hout + (size_t)pi * CDIM + colg * 8) = o;
    }
    __shared__ float red[2048];
    float s = block_reduce_128<0>(ssum, red);
    float q = block_reduce_128<0>(ssq, red);
    if (tid < 128) {
        partials[(size_t)blockIdx.x * 256 + tid] = s;
        partials[(size_t)blockIdx.x * 256 + 128 + tid] = q;
    }
}

// ---------------- GEMM: X = h @ W' + b'  (swapped MFMA: A=W'T frags, B=h frags)
// MODE 0: h_out = mish(X) bf16 + partial stats of mish(X)
// MODE 1: no store; partial stats of X + per-segment max/min of X (block == segment)
template <int MODE>
__global__ __launch_bounds__(256, 4) void k_gemm(const uint16_t* __restrict__ hin,
                                                 uint16_t* __restrict__ hout,
                                                 const uint16_t* __restrict__ wt,  // W'T [128][128] bf16
                                                 const float* __restrict__ bp,     // b' [128]
                                                 float* __restrict__ partials,
                                                 float* __restrict__ maxb, float* __restrict__ minb) {
    int tid = threadIdx.x;
    int lane = tid & 63;
    int wave = tid >> 6;
    int l15 = lane & 15;
    int l4 = lane >> 4;

    // A fragments: lane l15 = channel row j (within 16-tile), 8 contiguous k
    short8 bfrag[8][4];
#pragma unroll
    for (int jb = 0; jb < 8; jb++)
#pragma unroll
        for (int kk = 0; kk < 4; kk++)
            bfrag[jb][kk] = *(const short8*)(wt + (jb * 16 + l15) * CDIM + kk * 32 + l4 * 8);

    // readout-phase bias: thread owns channels (tid&15)*8..+8
    float bias_r[8];
#pragma unroll
    for (int e = 0; e < 8; e++) bias_r[e] = bp[(tid & 15) * 8 + e];

    float ssum[8], ssq[8], smax[8], smin[8];
#pragma unroll
    for (int e = 0; e < 8; e++) {
        ssum[e] = 0.f; ssq[e] = 0.f;
        smax[e] = -3.4e38f; smin[e] = 3.4e38f;
    }

    __shared__ float sm[64 * 132];  // stage [64 pts][132 stride]; aliased as red later

    size_t rowbase = (size_t)blockIdx.x * 256;

    short8 af[4], afn[4];
    {
        const uint16_t* ap = hin + (rowbase + wave * 16 + l15) * CDIM + l4 * 8;
#pragma unroll
        for (int kk = 0; kk < 4; kk++) af[kk] = *(const short8*)(ap + kk * 32);
    }

    for (int g = 0; g < 4; ++g) {
        if (g < 3) {
            const uint16_t* ap = hin + (rowbase + (size_t)(g + 1) * 64 + wave * 16 + l15) * CDIM + l4 * 8;
#pragma unroll
            for (int kk = 0; kk < 4; kk++) afn[kk] = *(const short8*)(ap + kk * 32);
        }
        f32x4 acc[8];
#pragma unroll
        for (int jb = 0; jb < 8; jb++) acc[jb] = (f32x4){0.f, 0.f, 0.f, 0.f};
#pragma unroll
        for (int kk = 0; kk < 4; kk++)
#pragma unroll
            for (int jb = 0; jb < 8; jb++)
                acc[jb] = __builtin_amdgcn_mfma_f32_16x16x32_bf16(bfrag[jb][kk], af[kk], acc[jb], 0, 0, 0);

        // D[j][m]: col=l15=point m, row j = jb*16 + l4*4 + r -> lane holds 4 consecutive
        // channels for point l15 -> single ds_write_b128 per jb
#pragma unroll
        for (int jb = 0; jb < 8; jb++)
            *(f32x4*)&sm[(wave * 16 + l15) * 132 + jb * 16 + l4 * 4] = acc[jb];
        __syncthreads();

        // readout: thread t -> rows (t>>4)+16*it, channels (t&15)*8..+8
        int rt = tid >> 4, cg = tid & 15;
#pragma unroll
        for (int it = 0; it < 4; ++it) {
            int lr = rt + (it << 4);
            const float4* rp = (const float4*)&sm[lr * 132 + cg * 8];
            float4 v0 = rp[0], v1 = rp[1];
            float v[8] = {v0.x, v0.y, v0.z, v0.w, v1.x, v1.y, v1.z, v1.w};
#pragma unroll
            for (int e = 0; e < 8; e++) v[e] += bias_r[e];
            if constexpr (MODE == 0) {
#pragma unroll
                for (int e = 0; e < 8; e++) v[e] = mish_f(v[e]);
                uint4 o;
                o.x = pack2(v[0], v[1]); o.y = pack2(v[2], v[3]);
                o.z = pack2(v[4], v[5]); o.w = pack2(v[6], v[7]);
                *(uint4*)(hout + (rowbase + (size_t)g * 64 + lr) * CDIM + cg * 8) = o;
            }
#pragma unroll
            for (int e = 0; e < 8; e++) {
                ssum[e] += v[e];
                ssq[e] += v[e] * v[e];
            }
            if constexpr (MODE == 1) {
#pragma unroll
                for (int e = 0; e < 8; e++) {
                    smax[e] = fmaxf(smax[e], v[e]);
                    smin[e] = fminf(smin[e], v[e]);
                }
            }
        }
        __syncthreads();
        if (g < 3) {
#pragma unroll
            for (int kk = 0; kk < 4; kk++) af[kk] = afn[kk];
        }
    }

    float s = block_reduce_128<0>(ssum, sm);
    float q = block_reduce_128<0>(ssq, sm);
    if (tid < 128) {
        partials[(size_t)blockIdx.x * 256 + tid] = s;
        partials[(size_t)blockIdx.x * 256 + 128 + tid] = q;
    }
    if constexpr (MODE == 1) {
        float mx = block_reduce_128<1>(smax, sm);
        float mn = block_reduce_128<2>(smin, sm);
        if (tid < 128) {
            maxb[(size_t)blockIdx.x * 128 + tid] = mx;
            minb[(size_t)blockIdx.x * 128 + tid] = mn;
        }
    }
}

// ---------------- reduce partials [4096][256] -> stats[256] (few spread atomics)
__global__ __launch_bounds__(256) void k_reduce(const float* __restrict__ partials,
                                                float* __restrict__ stats) {
    int c = threadIdx.x;
    int r0 = blockIdx.x * 64;
    float a = 0.f;
    for (int r = 0; r < 64; r++) a += partials[(size_t)(r0 + r) * 256 + c];
    atomicAdd(stats + c, a);
}

// ---------------- fold BN into next linear (parallel: block j, thread k)
// wt[j][k] = s[k]*W[k][j] (bf16); b'[j] = b[j] + sum_k t[k]*W[k][j]
__global__ __launch_bounds__(128) void k_fold(const float* __restrict__ gsum, const float* __restrict__ gsq,
                                              const float* __restrict__ gamma, const float* __restrict__ beta,
                                              const float* __restrict__ W, const float* __restrict__ b,
                                              uint16_t* __restrict__ wtt, float* __restrict__ bpp) {
    int j = blockIdx.x, k = threadIdx.x;
    float mean = gsum[k] * (1.0f / (float)NPTS);
    float var = gsq[k] * (1.0f / (float)NPTS) - mean * mean;
    float s = gamma[k] * rsqrtf(var + 1e-5f);
    float t = beta[k] - mean * s;
    float w = W[k * 128 + j];
    wtt[j * 128 + k] = (uint16_t)bf16rne(s * w);
    __shared__ float red[128];
    red[k] = t * w;
    __syncthreads();
#pragma unroll
    for (int off = 64; off >= 1; off >>= 1) {
        if (k < off) red[k] += red[k + off];
        __syncthreads();
    }
    if (k == 0) bpp[j] = b[j] + red[0];
}

// ---------------- last BN scale/shift
__global__ void k_lastbn(const float* __restrict__ gsum, const float* __restrict__ gsq,
                         const float* __restrict__ gamma, const float* __restrict__ beta,
                         float* __restrict__ st) {
    int c = threadIdx.x;
    float mean = gsum[c] * (1.0f / (float)NPTS);
    float var = gsq[c] * (1.0f / (float)NPTS) - mean * mean;
    float s = gamma[c] * rsqrtf(var + 1e-5f);
    st[c] = s;
    st[128 + c] = beta[c] - mean * s;
}

// ---------------- finalize: out[seg][c] = s*(s>=0 ? max : min) + t
__global__ __launch_bounds__(256) void k_final(const float* __restrict__ maxb,
                                               const float* __restrict__ minb,
                                               const float* __restrict__ st,
                                               float* __restrict__ out) {
    int idx = blockIdx.x * 256 + threadIdx.x;
    int c = idx & 127;
    float s = st[c], t = st[128 + c];
    out[idx] = fmaf(s, (s >= 0.f ? maxb[idx] : minb[idx]), t);
}

extern "C" void kernel_launch(void* const* d_in, const int* in_sizes, int n_in,
                              void* d_out, int out_size, void* d_ws, size_t ws_size,
                              hipStream_t stream) {
    const float2* pts = (const float2*)d_in[0];
    // d_in[1] segment_ids: contiguous equal segments of 256 -> implicit
    const float* wf = (const float*)d_in[2];
    const float* bfirst = (const float*)d_in[3];
    const float* mg = (const float*)d_in[4];
    const float* mb = (const float*)d_in[5];
    const float* mw = (const float*)d_in[6];
    const float* mbi = (const float*)d_in[7];
    const float* lg = (const float*)d_in[8];
    const float* lb = (const float*)d_in[9];
    float* out = (float*)d_out;

    const size_t H_BYTES = 268435456ull;                      // 1M x 128 bf16, in-place
    const size_t MM_BYTES = 2ull * 2097152;                   // maxb+minb
    const size_t PART_BYTES = 4194304ull;                     // partials [4096][256] f32
    const size_t NEED = H_BYTES + 6144 + 33280 + MM_BYTES + PART_BYTES;

    char* mem = nullptr;
    bool use_ws = (ws_size >= NEED);
    if (use_ws) {
        mem = (char*)d_ws;
    } else {
        if (hipMallocAsync((void**)&mem, NEED, stream) != hipSuccess || mem == nullptr) return;
    }

    uint16_t* hbuf = (uint16_t*)mem;
    float* stats = (float*)(mem + H_BYTES);              // 5 x (sum[128], sumsq[128])
    float* stl = (float*)(mem + H_BYTES + 5120);         // s_last[128], t_last[128]
    uint16_t* wt = (uint16_t*)(mem + H_BYTES + 6144);    // folded W'T bf16 [128][128]
    float* bp = (float*)(mem + H_BYTES + 6144 + 32768);  // folded b' [128]
    float* maxb = (float*)(mem + H_BYTES + 6144 + 33280);
    float* minb = maxb + (size_t)NSEG * CDIM;
    float* partials = (float*)(mem + H_BYTES + 6144 + 33280 + MM_BYTES);

    hipMemsetAsync(stats, 0, 5120, stream);
    k_first<<<4096, 256, 0, stream>>>(pts, wf, bfirst, hbuf, partials);
    k_reduce<<<64, 256, 0, stream>>>(partials, stats);
    for (int L = 0; L < 4; ++L) {
        k_fold<<<128, 128, 0, stream>>>(stats + L * 256, stats + L * 256 + 128,
                                        mg + L * 128, mb + L * 128,
                                        mw + (size_t)L * 16384, mbi + L * 128, wt, bp);
        if (L < 3)
            k_gemm<0><<<4096, 256, 0, stream>>>(hbuf, hbuf, wt, bp, partials, nullptr, nullptr);
        else
            k_gemm<1><<<4096, 256, 0, stream>>>(hbuf, nullptr, wt, bp, partials, maxb, minb);
        k_reduce<<<64, 256, 0, stream>>>(partials, stats + (L + 1) * 256);
    }
    k_lastbn<<<1, 128, 0, stream>>>(stats + 1024, stats + 1024 + 128, lg, lb, stl);
    k_final<<<2048, 256, 0, stream>>>(maxb, minb, stl, out);

    if (!use_ws) hipFreeAsync(mem, stream);
}

// Round 7
// 718.824 us; speedup vs baseline: 2.3438x; 2.3438x over previous
//
#include <hip/hip_runtime.h>
#include <hip/hip_bf16.h>
#include <cstdint>

#define NPTS (1u << 20)
#define CDIM 128
#define NSEG 4096

typedef __attribute__((ext_vector_type(8))) short short8;
typedef __attribute__((ext_vector_type(4))) float f32x4;

// ---- static device workspace: no hipMallocAsync inside kernel_launch.
// Graph capture sees ONLY kernel nodes -> launch_once and graph replay are
// byte-identical work on identical addresses (alloc/free graph nodes were the
// prime suspect for the round-4/6 determinism-tripwire failures).
#define H_BYTES   268435456ull                    // 1M x 128 bf16 activations (in-place)
#define STATS_OFF H_BYTES                         // 5 x (sum[128], sumsq[128]) f32
#define STL_OFF   (H_BYTES + 5120)                // s_last[128], t_last[128]
#define WT_OFF    (H_BYTES + 6144)                // folded W'T bf16 [128][128]
#define BP_OFF    (H_BYTES + 6144 + 32768)        // folded b' [128] f32
#define MAXB_OFF  (H_BYTES + 6144 + 33280)        // [4096][128] f32
#define MINB_OFF  (MAXB_OFF + 2097152ull)         // [4096][128] f32
#define PART_OFF  (MINB_OFF + 2097152ull)         // partials [4096][256] f32
#define P2_OFF    (PART_OFF + 4194304ull)         // partial2 [64][256] f32
#define WS_TOTAL  (P2_OFF + 65536ull)

__device__ __align__(256) unsigned char g_ws[WS_TOTAL];

__device__ __forceinline__ uint32_t bf16rne(float f) {
    uint32_t u = __float_as_uint(f);
    return (u + 0x7fffu + ((u >> 16) & 1u)) >> 16;
}
__device__ __forceinline__ uint32_t pack2(float a, float b) {
    union { __hip_bfloat162 h; uint32_t u; } cv;
    cv.h = __float22bfloat162_rn(make_float2(a, b));  // v_cvt_pk_bf16_f32, RNE
    return cv.u;
}
// mish(x) = x*tanh(softplus(x)) = x*(t^2+2t)/(t^2+2t+2), t=e^x (exact identity)
__device__ __forceinline__ float mish_f(float x) {
    float t = __expf(x);
    float u = t * (t + 2.0f);
    float m = x * u * __builtin_amdgcn_rcpf(u + 2.0f);
    return (x > 15.0f) ? x : m;
}

// block-wide per-channel reduce; thread t owns channels (t&15)*8+e.
// Returns (for tid<128) the block result for channel tid. red needs 2048 floats.
// Deterministic: fixed per-thread order.
template <int OP>  // 0=sum 1=max 2=min
__device__ __forceinline__ float block_reduce_128(float (&vals)[8], float* red) {
    int tid = threadIdx.x;
#pragma unroll
    for (int e = 0; e < 8; e++) red[tid * 8 + e] = vals[e];
    __syncthreads();
    float a = (OP == 0) ? 0.f : (OP == 1 ? -3.4e38f : 3.4e38f);
    if (tid < 128) {
        int cg = tid >> 3, e = tid & 7;
#pragma unroll
        for (int r = 0; r < 16; r++) {
            float x = red[(cg + (r << 4)) * 8 + e];
            if (OP == 0) a += x;
            else if (OP == 1) a = fmaxf(a, x);
            else a = fminf(a, x);
        }
    }
    __syncthreads();
    return a;
}

// ---------------- k0: h0 = mish(points @ w_first + b_first) (bf16) + partial stats
__global__ __launch_bounds__(256) void k_first(const float2* __restrict__ pts,
                                               const float* __restrict__ wf,
                                               const float* __restrict__ bf) {
    uint16_t* hout = (uint16_t*)g_ws;
    float* partials = (float*)(g_ws + PART_OFF);
    int tid = threadIdx.x;
    int colg = tid & 15;
    int rowt = tid >> 4;
    float w0[8], w1[8], bb[8];
#pragma unroll
    for (int e = 0; e < 8; e++) {
        w0[e] = wf[colg * 8 + e];
        w1[e] = wf[128 + colg * 8 + e];
        bb[e] = bf[colg * 8 + e];
    }
    float ssum[8], ssq[8];
#pragma unroll
    for (int e = 0; e < 8; e++) { ssum[e] = 0.f; ssq[e] = 0.f; }

    int base = blockIdx.x * 256;
    for (int p = 0; p < 16; p++) {
        int pi = base + p * 16 + rowt;
        float2 pt = pts[pi];
        float v[8];
#pragma unroll
        for (int e = 0; e < 8; e++) {
            float x = fmaf(pt.x, w0[e], fmaf(pt.y, w1[e], bb[e]));
            v[e] = mish_f(x);
            ssum[e] += v[e];
            ssq[e] += v[e] * v[e];
        }
        uint4 o;
        o.x = pack2(v[0], v[1]); o.y = pack2(v[2], v[3]);
        o.z = pack2(v[4], v[5]); o.w = pack2(v[6], v[7]);
        *(uint4*)(hout + (size_t)pi * CDIM + colg * 8) = o;
    }
    __shared__ float red[2048];
    float s = block_reduce_128<0>(ssum, red);
    float q = block_reduce_128<0>(ssq, red);
    if (tid < 128) {
        partials[(size_t)blockIdx.x * 256 + tid] = s;
        partials[(size_t)blockIdx.x * 256 + 128 + tid] = q;
    }
}

// ---------------- GEMM: X = h @ W' + b'  (swapped MFMA: A=W'T frags, B=h frags)
// MODE 0: h_out = mish(X) bf16 (in-place) + partial stats of mish(X)
// MODE 1: no store; partial stats of X + per-segment max/min of X (block == segment)
// NOTE: launch_bounds (256,2) — (256,4) forced VGPR=64 and spilled to scratch
// (FETCH 131->850 MB, dur 160->400 us). ~125 live VGPRs need the 256-reg budget.
template <int MODE>
__global__ __launch_bounds__(256, 2) void k_gemm() {
    uint16_t* hbuf = (uint16_t*)g_ws;
    const uint16_t* wt = (const uint16_t*)(g_ws + WT_OFF);
    const float* bp = (const float*)(g_ws + BP_OFF);
    float* partials = (float*)(g_ws + PART_OFF);
    float* maxb = (float*)(g_ws + MAXB_OFF);
    float* minb = (float*)(g_ws + MINB_OFF);

    int tid = threadIdx.x;
    int lane = tid & 63;
    int wave = tid >> 6;
    int l15 = lane & 15;
    int l4 = lane >> 4;

    // A fragments: lane l15 = channel row j (within 16-tile), 8 contiguous k
    short8 bfrag[8][4];
#pragma unroll
    for (int jb = 0; jb < 8; jb++)
#pragma unroll
        for (int kk = 0; kk < 4; kk++)
            bfrag[jb][kk] = *(const short8*)(wt + (jb * 16 + l15) * CDIM + kk * 32 + l4 * 8);

    // readout-phase bias: thread owns channels (tid&15)*8..+8
    float bias_r[8];
#pragma unroll
    for (int e = 0; e < 8; e++) bias_r[e] = bp[(tid & 15) * 8 + e];

    float ssum[8], ssq[8], smax[8], smin[8];
#pragma unroll
    for (int e = 0; e < 8; e++) {
        ssum[e] = 0.f; ssq[e] = 0.f;
        smax[e] = -3.4e38f; smin[e] = 3.4e38f;
    }

    __shared__ float sm[64 * 132];  // stage [64 pts][132 stride]; aliased as red later

    size_t rowbase = (size_t)blockIdx.x * 256;

    short8 af[4], afn[4];
    {
        const uint16_t* ap = hbuf + (rowbase + wave * 16 + l15) * CDIM + l4 * 8;
#pragma unroll
        for (int kk = 0; kk < 4; kk++) af[kk] = *(const short8*)(ap + kk * 32);
    }

    for (int g = 0; g < 4; ++g) {
        if (g < 3) {
            const uint16_t* ap = hbuf + (rowbase + (size_t)(g + 1) * 64 + wave * 16 + l15) * CDIM + l4 * 8;
#pragma unroll
            for (int kk = 0; kk < 4; kk++) afn[kk] = *(const short8*)(ap + kk * 32);
        }
        f32x4 acc[8];
#pragma unroll
        for (int jb = 0; jb < 8; jb++) acc[jb] = (f32x4){0.f, 0.f, 0.f, 0.f};
#pragma unroll
        for (int kk = 0; kk < 4; kk++)
#pragma unroll
            for (int jb = 0; jb < 8; jb++)
                acc[jb] = __builtin_amdgcn_mfma_f32_16x16x32_bf16(bfrag[jb][kk], af[kk], acc[jb], 0, 0, 0);

        // D[j][m]: col=l15=point m, row j = jb*16 + l4*4 + r -> lane holds 4 consecutive
        // channels for point l15 -> single ds_write_b128 per jb
#pragma unroll
        for (int jb = 0; jb < 8; jb++)
            *(f32x4*)&sm[(wave * 16 + l15) * 132 + jb * 16 + l4 * 4] = acc[jb];
        __syncthreads();

        // readout: thread t -> rows (t>>4)+16*it, channels (t&15)*8..+8
        int rt = tid >> 4, cg = tid & 15;
#pragma unroll
        for (int it = 0; it < 4; ++it) {
            int lr = rt + (it << 4);
            const float4* rp = (const float4*)&sm[lr * 132 + cg * 8];
            float4 v0 = rp[0], v1 = rp[1];
            float v[8] = {v0.x, v0.y, v0.z, v0.w, v1.x, v1.y, v1.z, v1.w};
#pragma unroll
            for (int e = 0; e < 8; e++) v[e] += bias_r[e];
            if constexpr (MODE == 0) {
#pragma unroll
                for (int e = 0; e < 8; e++) v[e] = mish_f(v[e]);
                uint4 o;
                o.x = pack2(v[0], v[1]); o.y = pack2(v[2], v[3]);
                o.z = pack2(v[4], v[5]); o.w = pack2(v[6], v[7]);
                *(uint4*)(hbuf + (rowbase + (size_t)g * 64 + lr) * CDIM + cg * 8) = o;
            }
#pragma unroll
            for (int e = 0; e < 8; e++) {
                ssum[e] += v[e];
                ssq[e] += v[e] * v[e];
            }
            if constexpr (MODE == 1) {
#pragma unroll
                for (int e = 0; e < 8; e++) {
                    smax[e] = fmaxf(smax[e], v[e]);
                    smin[e] = fminf(smin[e], v[e]);
                }
            }
        }
        __syncthreads();
        if (g < 3) {
#pragma unroll
            for (int kk = 0; kk < 4; kk++) af[kk] = afn[kk];
        }
    }

    float s = block_reduce_128<0>(ssum, sm);
    float q = block_reduce_128<0>(ssq, sm);
    if (tid < 128) {
        partials[(size_t)blockIdx.x * 256 + tid] = s;
        partials[(size_t)blockIdx.x * 256 + 128 + tid] = q;
    }
    if constexpr (MODE == 1) {
        float mx = block_reduce_128<1>(smax, sm);
        float mn = block_reduce_128<2>(smin, sm);
        if (tid < 128) {
            maxb[(size_t)blockIdx.x * 128 + tid] = mx;
            minb[(size_t)blockIdx.x * 128 + tid] = mn;
        }
    }
}

// ---------------- deterministic two-stage stats reduce (no atomics)
__global__ __launch_bounds__(256) void k_reduce1() {
    const float* partials = (const float*)(g_ws + PART_OFF);
    float* partial2 = (float*)(g_ws + P2_OFF);
    int c = threadIdx.x;
    int r0 = blockIdx.x * 64;
    float a = 0.f;
    for (int r = 0; r < 64; r++) a += partials[(size_t)(r0 + r) * 256 + c];
    partial2[blockIdx.x * 256 + c] = a;
}
__global__ __launch_bounds__(256) void k_reduce2(int Lout) {
    const float* partial2 = (const float*)(g_ws + P2_OFF);
    float* stats = (float*)(g_ws + STATS_OFF) + Lout * 256;
    int c = threadIdx.x;
    float a = 0.f;
    for (int r = 0; r < 64; r++) a += partial2[r * 256 + c];
    stats[c] = a;
}

// ---------------- fold BN into next linear (parallel: block j, thread k)
// wt[j][k] = s[k]*W[k][j] (bf16); b'[j] = b[j] + sum_k t[k]*W[k][j]
__global__ __launch_bounds__(128) void k_fold(int L,
                                              const float* __restrict__ gamma_all, const float* __restrict__ beta_all,
                                              const float* __restrict__ W_all, const float* __restrict__ b_all) {
    const float* gsum = (const float*)(g_ws + STATS_OFF) + L * 256;
    const float* gsq = gsum + 128;
    const float* gamma = gamma_all + L * 128;
    const float* beta = beta_all + L * 128;
    const float* W = W_all + (size_t)L * 16384;
    const float* b = b_all + L * 128;
    uint16_t* wtt = (uint16_t*)(g_ws + WT_OFF);
    float* bpp = (float*)(g_ws + BP_OFF);

    int j = blockIdx.x, k = threadIdx.x;
    float mean = gsum[k] * (1.0f / (float)NPTS);
    float var = gsq[k] * (1.0f / (float)NPTS) - mean * mean;
    float s = gamma[k] * rsqrtf(var + 1e-5f);
    float t = beta[k] - mean * s;
    float w = W[k * 128 + j];
    wtt[j * 128 + k] = (uint16_t)bf16rne(s * w);
    __shared__ float red[128];
    red[k] = t * w;
    __syncthreads();
#pragma unroll
    for (int off = 64; off >= 1; off >>= 1) {
        if (k < off) red[k] += red[k + off];
        __syncthreads();
    }
    if (k == 0) bpp[j] = b[j] + red[0];
}

// ---------------- last BN scale/shift
__global__ void k_lastbn(const float* __restrict__ gamma, const float* __restrict__ beta) {
    const float* gsum = (const float*)(g_ws + STATS_OFF) + 1024;
    const float* gsq = gsum + 128;
    float* st = (float*)(g_ws + STL_OFF);
    int c = threadIdx.x;
    float mean = gsum[c] * (1.0f / (float)NPTS);
    float var = gsq[c] * (1.0f / (float)NPTS) - mean * mean;
    float s = gamma[c] * rsqrtf(var + 1e-5f);
    st[c] = s;
    st[128 + c] = beta[c] - mean * s;
}

// ---------------- finalize: out[seg][c] = s*(s>=0 ? max : min) + t
__global__ __launch_bounds__(256) void k_final(float* __restrict__ out) {
    const float* maxb = (const float*)(g_ws + MAXB_OFF);
    const float* minb = (const float*)(g_ws + MINB_OFF);
    const float* st = (const float*)(g_ws + STL_OFF);
    int idx = blockIdx.x * 256 + threadIdx.x;
    int c = idx & 127;
    float s = st[c], t = st[128 + c];
    out[idx] = fmaf(s, (s >= 0.f ? maxb[idx] : minb[idx]), t);
}

extern "C" void kernel_launch(void* const* d_in, const int* in_sizes, int n_in,
                              void* d_out, int out_size, void* d_ws, size_t ws_size,
                              hipStream_t stream) {
    const float2* pts = (const float2*)d_in[0];
    // d_in[1] segment_ids: contiguous equal segments of 256 -> implicit
    const float* wf = (const float*)d_in[2];
    const float* bfirst = (const float*)d_in[3];
    const float* mg = (const float*)d_in[4];
    const float* mb = (const float*)d_in[5];
    const float* mw = (const float*)d_in[6];
    const float* mbi = (const float*)d_in[7];
    const float* lg = (const float*)d_in[8];
    const float* lb = (const float*)d_in[9];
    float* out = (float*)d_out;

    k_first<<<4096, 256, 0, stream>>>(pts, wf, bfirst);
    k_reduce1<<<64, 256, 0, stream>>>();
    k_reduce2<<<1, 256, 0, stream>>>(0);
    for (int L = 0; L < 4; ++L) {
        k_fold<<<128, 128, 0, stream>>>(L, mg, mb, mw, mbi);
        if (L < 3)
            k_gemm<0><<<4096, 256, 0, stream>>>();
        else
            k_gemm<1><<<4096, 256, 0, stream>>>();
        k_reduce1<<<64, 256, 0, stream>>>();
        k_reduce2<<<1, 256, 0, stream>>>(L + 1);
    }
    k_lastbn<<<1, 128, 0, stream>>>(lg, lb);
    k_final<<<2048, 256, 0, stream>>>(out);
}